// Round 8
// baseline (340.480 us; speedup 1.0000x reference)
//
#include <hip/hip_runtime.h>
#include <hip/hip_bf16.h>
#include <stdint.h>

#define T_TOK 4096
#define NEXP  8
#define HDIM  1024
#define IDIM  2048
#define TOPK  2

typedef __attribute__((ext_vector_type(8))) short short8;
typedef __attribute__((ext_vector_type(4))) float f32x4;

__device__ __forceinline__ unsigned short f2bf(float f) {
    union { float f; unsigned int u; } v; v.f = f;
    unsigned int u = v.u;
    return (unsigned short)((u + 0x7fffu + ((u >> 16) & 1u)) >> 16);
}
__device__ __forceinline__ unsigned short f2bf_hu(float f) {   // round-half-up (2 ops)
    union { float f; unsigned int u; } v; v.f = f;
    return (unsigned short)((v.u + 0x8000u) >> 16);
}
__device__ __forceinline__ float bf2f(unsigned short s) {
    union { unsigned int u; float f; } v; v.u = ((unsigned int)s) << 16;
    return v.f;
}
__device__ __forceinline__ void gload_lds16(const void* g, void* l) {
    __builtin_amdgcn_global_load_lds(
        (const __attribute__((address_space(1))) unsigned int*)g,
        (__attribute__((address_space(3))) unsigned int*)l,
        16, 0, 0);
}
#define MFMA16(A, B, C) __builtin_amdgcn_mfma_f32_16x16x32_bf16(A, B, C, 0, 0, 0)

// ---------------- routing ----------------

__global__ void init_k(int* cnt) {
    if (threadIdx.x < NEXP) cnt[threadIdx.x] = 0;
}

__global__ void router_k(const float* __restrict__ logits, int* __restrict__ cnt,
                         int* __restrict__ eids, float* __restrict__ ews) {
    int t = blockIdx.x * blockDim.x + threadIdx.x;
    if (t >= T_TOK) return;
    const float4* lp = (const float4*)(logits + (size_t)t * NEXP);
    float4 a = lp[0], b = lp[1];
    float l[NEXP] = {a.x, a.y, a.z, a.w, b.x, b.y, b.z, b.w};
    int e0 = 0; float b0 = l[0];
    #pragma unroll
    for (int e = 1; e < NEXP; ++e) if (l[e] > b0) { b0 = l[e]; e0 = e; }
    int e1 = -1; float b1 = -1e30f;
    #pragma unroll
    for (int e = 0; e < NEXP; ++e) { if (e == e0) continue; if (l[e] > b1) { b1 = l[e]; e1 = e; } }
    float tt = __expf(b1 - b0);
    float w0 = 1.0f / (1.0f + tt);
    float w1 = 1.0f - w0;
    eids[2 * t] = e0; eids[2 * t + 1] = e1;
    ews[2 * t] = w0;  ews[2 * t + 1] = w1;
    atomicAdd(&cnt[e0], 1); atomicAdd(&cnt[e1], 1);
}

__global__ void offs_k(const int* __restrict__ cnt, int* __restrict__ offs,
                       int* __restrict__ cursor, int* __restrict__ work) {
    if (threadIdx.x == 0) {
        int s = 0, n = 0;
        for (int e = 0; e < NEXP; ++e) {
            offs[e] = s; cursor[e] = s;
            int nm = (cnt[e] + 255) >> 8;
            for (int m = 0; m < nm; ++m) work[1 + n++] = (e << 8) | m;
            s += cnt[e];
        }
        offs[NEXP] = s;
        work[0] = n;
    }
}

__global__ void scatter_k(const int* __restrict__ eids, const float* __restrict__ ews,
                          int* __restrict__ cursor, int* __restrict__ tokid,
                          float* __restrict__ tokw, int* __restrict__ pos) {
    int t = blockIdx.x * blockDim.x + threadIdx.x;
    if (t >= T_TOK) return;
    #pragma unroll
    for (int k = 0; k < TOPK; ++k) {
        int e = eids[2 * t + k];
        int p = atomicAdd(&cursor[e], 1);
        tokid[p] = t; tokw[p] = ews[2 * t + k]; pos[2 * t + k] = p;
    }
}

// ---------------- fp32 -> bf16 convert: x only (2 MB out) ----------------

__global__ void cvt_x_k(const float* __restrict__ x, unsigned short* __restrict__ xb) {
    int i = blockIdx.x * blockDim.x + threadIdx.x;   // T*H/8 threads
    const float4* p = (const float4*)(x + (size_t)i * 8);
    float4 a = p[0], b = p[1];
    union { unsigned short us[8]; short8 v; } r;
    r.us[0] = f2bf(a.x); r.us[1] = f2bf(a.y); r.us[2] = f2bf(a.z); r.us[3] = f2bf(a.w);
    r.us[4] = f2bf(b.x); r.us[5] = f2bf(b.y); r.us[6] = f2bf(b.z); r.us[7] = f2bf(b.w);
    *(short8*)(xb + (size_t)i * 8) = r.v;
}

// ---------------- GEMM1: h = silu(x@W1^T) * (x@W3^T) ----------------
// BM=256 tokens x BN=256 B-rows (128 gate + 128 up), BK=64, 8 waves (2M x 4N).
// A (tokens, bf16 xb): global_load_lds. B (weights): read fp32 w13 DIRECTLY,
// convert in-register to bf16, ds_write (saves the cvt kernel's 400MB round trip).
// B loads for tile kt+1 issue at top of iter kt; cvt+write after MFMA (T14).
// LDS: 2 x (A[256][64] + B[256][64]) bf16 = 128KB. Swizzle: slot = l16 ^ (row&7)
// (R1-proven, 0 conflicts). grid (16,40), work-list, XCD-chunked swizzle.

#define G1SLOT 32768   // ushorts per K-tile buffer

__global__ __launch_bounds__(512, 1) void gemm1_k(
    const unsigned short* __restrict__ xb, const float* __restrict__ w13,
    const int* __restrict__ tokid, const int* __restrict__ offs,
    const int* __restrict__ work, unsigned short* __restrict__ hbuf)
{
    extern __shared__ unsigned short lds[];
    // XCD-chunked bijective swizzle (nwg=640, q=80): XCD x gets nt {2x,2x+1}
    const int id = blockIdx.y * gridDim.x + blockIdx.x;
    const int id2 = (id & 7) * 80 + (id >> 3);
    const int nt = id2 / 40;
    const int wki = id2 % 40;
    const int nw = work[0];
    if (wki >= nw) return;
    const int wk = work[1 + wki];
    const int e = wk >> 8, mt = wk & 255;
    const int off_e = offs[e];
    const int cnt_e = offs[e + 1] - off_e;

    const int tid = threadIdx.x;
    const int w = tid >> 6, lane = tid & 63;
    const int ln15 = lane & 15, l16 = lane >> 4;
    const int wm = w >> 2, wn = w & 3;

    // A staging: 4 x gload_lds16 per tile (bf16, linear LDS, source inverse-swizzled)
    const unsigned short* srcA[4]; int dstA[4];
    #pragma unroll
    for (int j = 0; j < 4; ++j) {
        int S = j * 512 + tid;
        int row = S >> 3, p = S & 7;
        int kl = p ^ (row & 7);
        int tr = mt * 256 + row; if (tr >= cnt_e) tr = cnt_e - 1;
        srcA[j] = xb + (size_t)tokid[off_e + tr] * HDIM + kl * 8;
        dstA[j] = S * 8;
    }
    // B staging: fp32 source, reg round trip; thread owns 4 x 16B bf16 dst slots
    const float* srcB[4]; int dstB[4];
    #pragma unroll
    for (int j = 0; j < 4; ++j) {
        int S = j * 512 + tid;
        int row = S >> 3, p = S & 7;
        int ksl = p ^ (row & 7);
        int grp = row >> 6, q = (row >> 5) & 1, sub = row & 31;
        int grow = q * IDIM + nt * 128 + grp * 32 + sub;
        srcB[j] = w13 + (size_t)e * (2 * IDIM * HDIM) + (size_t)grow * HDIM + ksl * 8;
        dstB[j] = 16384 + S * 8;
    }

    const f32x4 z4 = {0.f, 0.f, 0.f, 0.f};
    f32x4 acc[8][4];
    #pragma unroll
    for (int m = 0; m < 8; ++m)
        #pragma unroll
        for (int n = 0; n < 4; ++n) acc[m][n] = z4;

    // fragment read offsets (ushort units): slot = (kk*4+l16) ^ (row&7)
    const int g = ln15 & 7;
    const int sl0 = ((0 + l16) ^ g) * 8;
    const int sl1 = ((4 + l16) ^ g) * 8;
    const int arow = (wm * 128 + ln15) * 64;
    const int brow = 16384 + (wn * 64 + ln15) * 64;

    // prologue: tile 0 — issue B fp32 loads + A gloads, cvt+write B, sync
    {
        float4 bW[4][2];
        #pragma unroll
        for (int j = 0; j < 4; ++j) {
            bW[j][0] = *(const float4*)(srcB[j]);
            bW[j][1] = *(const float4*)(srcB[j] + 4);
        }
        #pragma unroll
        for (int j = 0; j < 4; ++j) gload_lds16(srcA[j], lds + dstA[j]);
        #pragma unroll
        for (int j = 0; j < 4; ++j) {
            union { unsigned short us[8]; short8 v; } pk;
            pk.us[0] = f2bf_hu(bW[j][0].x); pk.us[1] = f2bf_hu(bW[j][0].y);
            pk.us[2] = f2bf_hu(bW[j][0].z); pk.us[3] = f2bf_hu(bW[j][0].w);
            pk.us[4] = f2bf_hu(bW[j][1].x); pk.us[5] = f2bf_hu(bW[j][1].y);
            pk.us[6] = f2bf_hu(bW[j][1].z); pk.us[7] = f2bf_hu(bW[j][1].w);
            *(short8*)&lds[dstB[j]] = pk.v;
        }
        asm volatile("s_waitcnt vmcnt(0)" ::: "memory");
        __syncthreads();
    }

    const int KT = HDIM / 64;   // 16
    for (int kt = 0; kt < KT; ++kt) {
        const unsigned short* buf = lds + (kt & 1) * G1SLOT;
        unsigned short* nbuf = lds + ((kt + 1) & 1) * G1SLOT;
        const bool notlast = (kt + 1 < KT);
        const int ko = (kt + 1) * 64;   // float / bf16 element offset

        // issue next tile's loads first (MFMA window covers their latency)
        float4 bW[4][2];
        if (notlast) {
            #pragma unroll
            for (int j = 0; j < 4; ++j) {
                bW[j][0] = *(const float4*)(srcB[j] + ko);
                bW[j][1] = *(const float4*)(srcB[j] + ko + 4);
            }
            #pragma unroll
            for (int j = 0; j < 4; ++j) gload_lds16(srcA[j] + ko, nbuf + dstA[j]);
        }
        // fragment reads + MFMA (compiler interleaves lgkmcnt)
        short8 a0[8], a1[8], b0[4], b1[4];
        #pragma unroll
        for (int m = 0; m < 8; ++m) a0[m] = *(const short8*)&buf[arow + m * 1024 + sl0];
        #pragma unroll
        for (int n = 0; n < 4; ++n) b0[n] = *(const short8*)&buf[brow + n * 1024 + sl0];
        __builtin_amdgcn_s_setprio(1);
        #pragma unroll
        for (int m = 0; m < 8; ++m)
            #pragma unroll
            for (int n = 0; n < 4; ++n)
                acc[m][n] = MFMA16(a0[m], b0[n], acc[m][n]);
        __builtin_amdgcn_s_setprio(0);
        #pragma unroll
        for (int m = 0; m < 8; ++m) a1[m] = *(const short8*)&buf[arow + m * 1024 + sl1];
        #pragma unroll
        for (int n = 0; n < 4; ++n) b1[n] = *(const short8*)&buf[brow + n * 1024 + sl1];
        __builtin_amdgcn_s_setprio(1);
        #pragma unroll
        for (int m = 0; m < 8; ++m)
            #pragma unroll
            for (int n = 0; n < 4; ++n)
                acc[m][n] = MFMA16(a1[m], b1[n], acc[m][n]);
        __builtin_amdgcn_s_setprio(0);
        // convert + write next B tile (loads have had the whole MFMA window)
        if (notlast) {
            #pragma unroll
            for (int j = 0; j < 4; ++j) {
                union { unsigned short us[8]; short8 v; } pk;
                pk.us[0] = f2bf_hu(bW[j][0].x); pk.us[1] = f2bf_hu(bW[j][0].y);
                pk.us[2] = f2bf_hu(bW[j][0].z); pk.us[3] = f2bf_hu(bW[j][0].w);
                pk.us[4] = f2bf_hu(bW[j][1].x); pk.us[5] = f2bf_hu(bW[j][1].y);
                pk.us[6] = f2bf_hu(bW[j][1].z); pk.us[7] = f2bf_hu(bW[j][1].w);
                *(short8*)&nbuf[dstB[j]] = pk.v;
            }
            asm volatile("s_waitcnt vmcnt(0)" ::: "memory");  // A gloads landed
        }
        __syncthreads();
    }

    // epilogue: silu(gate)*up -> bf16; n-frags 0,1 = gate, 2,3 = up (same cols)
    #pragma unroll
    for (int m = 0; m < 8; ++m) {
        #pragma unroll
        for (int i = 0; i < 4; ++i) {
            int r = mt * 256 + wm * 128 + m * 16 + l16 * 4 + i;
            if (r >= cnt_e) continue;
            size_t rb = (size_t)(off_e + r) * IDIM;
            #pragma unroll
            for (int nn = 0; nn < 2; ++nn) {
                int col = nt * 128 + wn * 32 + nn * 16 + ln15;
                float gv = acc[m][nn][i], uv = acc[m][2 + nn][i];
                float hv = gv / (1.f + __expf(-gv)) * uv;
                hbuf[rb + col] = f2bf(hv);
            }
        }
    }
}

// ---------------- GEMM2: pb = bf16( tokw * (h @ W2^T) ) ----------------
// BM=256, BN=128, BK=64, 8 waves (4M x 2N). A = hbuf bf16 (gload_lds);
// B = w2 fp32 direct (reg cvt). LDS 2 x 48KB = 96KB.
// grid (8,40), work-list, XCD swizzle (one nt per XCD).

#define G2SLOT 24576

__global__ __launch_bounds__(512, 1) void gemm2_k(
    const unsigned short* __restrict__ hbuf, const float* __restrict__ w2,
    const int* __restrict__ offs, const int* __restrict__ work,
    const float* __restrict__ tokw, unsigned short* __restrict__ pb)
{
    extern __shared__ unsigned short lds[];
    const int id = blockIdx.y * gridDim.x + blockIdx.x;   // 0..319
    const int id2 = (id & 7) * 40 + (id >> 3);
    const int nt = id2 / 40;
    const int wki = id2 % 40;
    const int nw = work[0];
    if (wki >= nw) return;
    const int wk = work[1 + wki];
    const int e = wk >> 8, mt = wk & 255;
    const int off_e = offs[e];
    const int cnt_e = offs[e + 1] - off_e;

    const int tid = threadIdx.x;
    const int w = tid >> 6, lane = tid & 63;
    const int ln15 = lane & 15, l16 = lane >> 4;
    const int wm = w >> 1, wn = w & 1;

    const unsigned short* srcA[4]; int dstA[4];
    #pragma unroll
    for (int j = 0; j < 4; ++j) {
        int S = j * 512 + tid;
        int row = S >> 3, p = S & 7;
        int kl = p ^ (row & 7);
        int tr = mt * 256 + row; if (tr >= cnt_e) tr = cnt_e - 1;
        srcA[j] = hbuf + (size_t)(off_e + tr) * IDIM + kl * 8;
        dstA[j] = S * 8;
    }
    const float* srcB[2]; int dstB[2];
    #pragma unroll
    for (int j = 0; j < 2; ++j) {
        int S = j * 512 + tid;
        int row = S >> 3, p = S & 7;
        int ksl = p ^ (row & 7);
        srcB[j] = w2 + (size_t)e * (HDIM * IDIM) + (size_t)(nt * 128 + row) * IDIM + ksl * 8;
        dstB[j] = 16384 + S * 8;
    }

    const f32x4 z4 = {0.f, 0.f, 0.f, 0.f};
    f32x4 acc[4][4];
    #pragma unroll
    for (int m = 0; m < 4; ++m)
        #pragma unroll
        for (int n = 0; n < 4; ++n) acc[m][n] = z4;

    const int g = ln15 & 7;
    const int sl0 = ((0 + l16) ^ g) * 8;
    const int sl1 = ((4 + l16) ^ g) * 8;
    const int arow = (wm * 64 + ln15) * 64;
    const int brow = 16384 + (wn * 64 + ln15) * 64;

    {
        float4 bW[2][2];
        #pragma unroll
        for (int j = 0; j < 2; ++j) {
            bW[j][0] = *(const float4*)(srcB[j]);
            bW[j][1] = *(const float4*)(srcB[j] + 4);
        }
        #pragma unroll
        for (int j = 0; j < 4; ++j) gload_lds16(srcA[j], lds + dstA[j]);
        #pragma unroll
        for (int j = 0; j < 2; ++j) {
            union { unsigned short us[8]; short8 v; } pk;
            pk.us[0] = f2bf_hu(bW[j][0].x); pk.us[1] = f2bf_hu(bW[j][0].y);
            pk.us[2] = f2bf_hu(bW[j][0].z); pk.us[3] = f2bf_hu(bW[j][0].w);
            pk.us[4] = f2bf_hu(bW[j][1].x); pk.us[5] = f2bf_hu(bW[j][1].y);
            pk.us[6] = f2bf_hu(bW[j][1].z); pk.us[7] = f2bf_hu(bW[j][1].w);
            *(short8*)&lds[dstB[j]] = pk.v;
        }
        asm volatile("s_waitcnt vmcnt(0)" ::: "memory");
        __syncthreads();
    }

    const int KT = IDIM / 64;   // 32
    for (int kt = 0; kt < KT; ++kt) {
        const unsigned short* buf = lds + (kt & 1) * G2SLOT;
        unsigned short* nbuf = lds + ((kt + 1) & 1) * G2SLOT;
        const bool notlast = (kt + 1 < KT);
        const int ko = (kt + 1) * 64;

        float4 bW[2][2];
        if (notlast) {
            #pragma unroll
            for (int j = 0; j < 2; ++j) {
                bW[j][0] = *(const float4*)(srcB[j] + ko);
                bW[j][1] = *(const float4*)(srcB[j] + ko + 4);
            }
            #pragma unroll
            for (int j = 0; j < 4; ++j) gload_lds16(srcA[j] + ko, nbuf + dstA[j]);
        }
        short8 a0[4], a1[4], b0[4], b1[4];
        #pragma unroll
        for (int m = 0; m < 4; ++m) a0[m] = *(const short8*)&buf[arow + m * 1024 + sl0];
        #pragma unroll
        for (int n = 0; n < 4; ++n) b0[n] = *(const short8*)&buf[brow + n * 1024 + sl0];
        __builtin_amdgcn_s_setprio(1);
        #pragma unroll
        for (int m = 0; m < 4; ++m)
            #pragma unroll
            for (int n = 0; n < 4; ++n)
                acc[m][n] = MFMA16(a0[m], b0[n], acc[m][n]);
        __builtin_amdgcn_s_setprio(0);
        #pragma unroll
        for (int m = 0; m < 4; ++m) a1[m] = *(const short8*)&buf[arow + m * 1024 + sl1];
        #pragma unroll
        for (int n = 0; n < 4; ++n) b1[n] = *(const short8*)&buf[brow + n * 1024 + sl1];
        __builtin_amdgcn_s_setprio(1);
        #pragma unroll
        for (int m = 0; m < 4; ++m)
            #pragma unroll
            for (int n = 0; n < 4; ++n)
                acc[m][n] = MFMA16(a1[m], b1[n], acc[m][n]);
        __builtin_amdgcn_s_setprio(0);
        if (notlast) {
            #pragma unroll
            for (int j = 0; j < 2; ++j) {
                union { unsigned short us[8]; short8 v; } pk;
                pk.us[0] = f2bf_hu(bW[j][0].x); pk.us[1] = f2bf_hu(bW[j][0].y);
                pk.us[2] = f2bf_hu(bW[j][0].z); pk.us[3] = f2bf_hu(bW[j][0].w);
                pk.us[4] = f2bf_hu(bW[j][1].x); pk.us[5] = f2bf_hu(bW[j][1].y);
                pk.us[6] = f2bf_hu(bW[j][1].z); pk.us[7] = f2bf_hu(bW[j][1].w);
                *(short8*)&nbuf[dstB[j]] = pk.v;
            }
            asm volatile("s_waitcnt vmcnt(0)" ::: "memory");
        }
        __syncthreads();
    }

    #pragma unroll
    for (int m = 0; m < 4; ++m) {
        #pragma unroll
        for (int i = 0; i < 4; ++i) {
            int r = mt * 256 + wm * 64 + m * 16 + l16 * 4 + i;
            if (r >= cnt_e) continue;
            float wgt = tokw[off_e + r];
            size_t rb = (size_t)(off_e + r) * HDIM;
            #pragma unroll
            for (int n = 0; n < 4; ++n) {
                int col = nt * 128 + wn * 64 + n * 16 + ln15;
                pb[rb + col] = f2bf(wgt * acc[m][n][i]);
            }
        }
    }
}

// ---------------- combine ----------------

__global__ void combine2_k(const unsigned short* __restrict__ pb, const int* __restrict__ pos,
                           float* __restrict__ out) {
    int idx = blockIdx.x * blockDim.x + threadIdx.x;   // T*H/8 threads
    int t = idx >> 7, c8 = idx & 127;
    int p0 = pos[2 * t], p1 = pos[2 * t + 1];
    short8 a = *(const short8*)(pb + (size_t)p0 * HDIM + c8 * 8);
    short8 b = *(const short8*)(pb + (size_t)p1 * HDIM + c8 * 8);
    float4 o0, o1;
    o0.x = bf2f((unsigned short)a[0]) + bf2f((unsigned short)b[0]);
    o0.y = bf2f((unsigned short)a[1]) + bf2f((unsigned short)b[1]);
    o0.z = bf2f((unsigned short)a[2]) + bf2f((unsigned short)b[2]);
    o0.w = bf2f((unsigned short)a[3]) + bf2f((unsigned short)b[3]);
    o1.x = bf2f((unsigned short)a[4]) + bf2f((unsigned short)b[4]);
    o1.y = bf2f((unsigned short)a[5]) + bf2f((unsigned short)b[5]);
    o1.z = bf2f((unsigned short)a[6]) + bf2f((unsigned short)b[6]);
    o1.w = bf2f((unsigned short)a[7]) + bf2f((unsigned short)b[7]);
    float* op = out + (size_t)t * HDIM + c8 * 8;
    ((float4*)op)[0] = o0;
    ((float4*)op)[1] = o1;
}

// ---------------- launch ----------------

extern "C" void kernel_launch(void* const* d_in, const int* in_sizes, int n_in,
                              void* d_out, int out_size, void* d_ws, size_t ws_size,
                              hipStream_t stream) {
    const float* x      = (const float*)d_in[0];
    const float* logits = (const float*)d_in[1];
    const float* w13    = (const float*)d_in[2];
    const float* w2     = (const float*)d_in[3];
    float* out = (float*)d_out;

    char* ws = (char*)d_ws;
    size_t off = 0;
    auto carve = [&](size_t bytes) -> void* {
        void* p = ws + off;
        off = (off + bytes + 255) & ~(size_t)255;
        return p;
    };
    int*   cnt    = (int*)carve(NEXP * 4);
    int*   offs   = (int*)carve((NEXP + 1) * 4);
    int*   cursor = (int*)carve(NEXP * 4);
    int*   work   = (int*)carve(64 * 4);
    int*   eids   = (int*)carve((size_t)T_TOK * 2 * 4);
    float* ews    = (float*)carve((size_t)T_TOK * 2 * 4);
    int*   tokid  = (int*)carve((size_t)(T_TOK * TOPK + 256) * 4);
    float* tokw   = (float*)carve((size_t)T_TOK * TOPK * 4);
    int*   pos    = (int*)carve((size_t)T_TOK * TOPK * 4);
    unsigned short* xb   = (unsigned short*)carve((size_t)T_TOK * HDIM * 2);
    unsigned short* hbuf = (unsigned short*)carve((size_t)T_TOK * TOPK * IDIM * 2);
    unsigned short* pb   = (unsigned short*)carve((size_t)T_TOK * TOPK * HDIM * 2);

    hipFuncSetAttribute(reinterpret_cast<const void*>(gemm1_k),
                        hipFuncAttributeMaxDynamicSharedMemorySize, 2 * G1SLOT * 2);
    hipFuncSetAttribute(reinterpret_cast<const void*>(gemm2_k),
                        hipFuncAttributeMaxDynamicSharedMemorySize, 2 * G2SLOT * 2);

    init_k<<<1, 64, 0, stream>>>(cnt);
    router_k<<<T_TOK / 256, 256, 0, stream>>>(logits, cnt, eids, ews);
    offs_k<<<1, 1, 0, stream>>>(cnt, offs, cursor, work);
    scatter_k<<<T_TOK / 256, 256, 0, stream>>>(eids, ews, cursor, tokid, tokw, pos);

    cvt_x_k<<<(T_TOK * HDIM / 8) / 256, 256, 0, stream>>>(x, xb);

    gemm1_k<<<dim3(16, 40, 1), 512, 2 * G1SLOT * 2, stream>>>(xb, w13, tokid, offs, work, hbuf);
    gemm2_k<<<dim3(8, 40, 1), 512, 2 * G2SLOT * 2, stream>>>(hbuf, w2, offs, work, tokw, pb);

    combine2_k<<<(T_TOK * HDIM / 8) / 256, 256, 0, stream>>>(pb, pos, out);
}

// Round 9
// 287.960 us; speedup vs baseline: 1.1824x; 1.1824x over previous
//
#include <hip/hip_runtime.h>
#include <hip/hip_bf16.h>
#include <stdint.h>

#define T_TOK 4096
#define NEXP  8
#define HDIM  1024
#define IDIM  2048
#define TOPK  2

typedef __attribute__((ext_vector_type(8))) short short8;
typedef __attribute__((ext_vector_type(4))) float f32x4;

__device__ __forceinline__ unsigned short f2bf(float f) {
    union { float f; unsigned int u; } v; v.f = f;
    unsigned int u = v.u;
    return (unsigned short)((u + 0x7fffu + ((u >> 16) & 1u)) >> 16);
}
__device__ __forceinline__ float bf2f(unsigned short s) {
    union { unsigned int u; float f; } v; v.u = ((unsigned int)s) << 16;
    return v.f;
}
__device__ __forceinline__ void gload_lds16(const void* g, void* l) {
    __builtin_amdgcn_global_load_lds(
        (const __attribute__((address_space(1))) unsigned int*)g,
        (__attribute__((address_space(3))) unsigned int*)l,
        16, 0, 0);
}
#define MFMA16(A, B, C) __builtin_amdgcn_mfma_f32_16x16x32_bf16(A, B, C, 0, 0, 0)

// ---------------- routing ----------------

__global__ void init_k(int* cnt) {
    if (threadIdx.x < NEXP) cnt[threadIdx.x] = 0;
}

__global__ void router_k(const float* __restrict__ logits, int* __restrict__ cnt,
                         int* __restrict__ eids, float* __restrict__ ews) {
    int t = blockIdx.x * blockDim.x + threadIdx.x;
    if (t >= T_TOK) return;
    const float4* lp = (const float4*)(logits + (size_t)t * NEXP);
    float4 a = lp[0], b = lp[1];
    float l[NEXP] = {a.x, a.y, a.z, a.w, b.x, b.y, b.z, b.w};
    int e0 = 0; float b0 = l[0];
    #pragma unroll
    for (int e = 1; e < NEXP; ++e) if (l[e] > b0) { b0 = l[e]; e0 = e; }
    int e1 = -1; float b1 = -1e30f;
    #pragma unroll
    for (int e = 0; e < NEXP; ++e) { if (e == e0) continue; if (l[e] > b1) { b1 = l[e]; e1 = e; } }
    float tt = __expf(b1 - b0);
    float w0 = 1.0f / (1.0f + tt);
    float w1 = 1.0f - w0;
    eids[2 * t] = e0; eids[2 * t + 1] = e1;
    ews[2 * t] = w0;  ews[2 * t + 1] = w1;
    atomicAdd(&cnt[e0], 1); atomicAdd(&cnt[e1], 1);
}

// offsets + (e,mt) work list for BM=128 blocks (shared by both GEMMs)
__global__ void offs_k(const int* __restrict__ cnt, int* __restrict__ offs,
                       int* __restrict__ cursor, int* __restrict__ work) {
    if (threadIdx.x == 0) {
        int s = 0, n = 0;
        for (int e = 0; e < NEXP; ++e) {
            offs[e] = s; cursor[e] = s;
            int nm = (cnt[e] + 127) >> 7;
            for (int m = 0; m < nm; ++m) work[1 + n++] = (e << 8) | m;
            s += cnt[e];
        }
        offs[NEXP] = s;
        work[0] = n;   // n <= 71
    }
}

__global__ void scatter_k(const int* __restrict__ eids, const float* __restrict__ ews,
                          int* __restrict__ cursor, int* __restrict__ tokid,
                          float* __restrict__ tokw, int* __restrict__ pos) {
    int t = blockIdx.x * blockDim.x + threadIdx.x;
    if (t >= T_TOK) return;
    #pragma unroll
    for (int k = 0; k < TOPK; ++k) {
        int e = eids[2 * t + k];
        int p = atomicAdd(&cursor[e], 1);
        tokid[p] = t; tokw[p] = ews[2 * t + k]; pos[2 * t + k] = p;
    }
}

// ---------------- convert weights + gather tokens (sorted order) ----------------
// xg[p][:] = bf16(x[tokid[p]][:])  -> GEMM1 A-staging becomes contiguous.

__global__ void cvt_all_k(const float* __restrict__ x, const float* __restrict__ w13,
                          const float* __restrict__ w2, const int* __restrict__ tokid,
                          unsigned short* __restrict__ xg, unsigned short* __restrict__ w13b,
                          unsigned short* __restrict__ w2b) {
    const int n0 = T_TOK * TOPK * HDIM / 8;          // gathered tokens
    const int n1 = NEXP * 2 * IDIM * HDIM / 8;
    const int n2 = NEXP * HDIM * IDIM / 8;
    const int total = n0 + n1 + n2;
    for (int i = blockIdx.x * blockDim.x + threadIdx.x; i < total; i += gridDim.x * blockDim.x) {
        const float* s; unsigned short* d; size_t js, jd;
        if (i < n0) {
            int p = i >> 7, c8 = i & 127;            // HDIM/8 = 128 chunks per row
            s = x; d = xg;
            js = (size_t)tokid[p] * HDIM + (size_t)c8 * 8;
            jd = (size_t)i * 8;
        } else if (i < n0 + n1) {
            int j = i - n0; s = w13; d = w13b; js = (size_t)j * 8; jd = js;
        } else {
            int j = i - n0 - n1; s = w2; d = w2b; js = (size_t)j * 8; jd = js;
        }
        const float4* p4 = (const float4*)(s + js);
        float4 a = p4[0], b = p4[1];
        union { unsigned short us[8]; short8 v; } r;
        r.us[0] = f2bf(a.x); r.us[1] = f2bf(a.y); r.us[2] = f2bf(a.z); r.us[3] = f2bf(a.w);
        r.us[4] = f2bf(b.x); r.us[5] = f2bf(b.y); r.us[6] = f2bf(b.z); r.us[7] = f2bf(b.w);
        *(short8*)(d + jd) = r.v;
    }
}

// ---------------- GEMM1: h = silu(x@W1^T) * (x@W3^T) ----------------
// R1-proven structure: 128 tokens x 128 cols (gate+up), BK=64, 256 thr / 4 waves
// (2x2), wave tile 64x64 on both matrices. Single-buffer LDS 48KB -> 3 blocks/CU
// (cross-block overlap hides barrier drains). A from xg (contiguous).
// grid (16, 72): work-list + XCD-chunked swizzle (nwg=1152, q=144).

__global__ __launch_bounds__(256, 2) void gemm1_k(
    const unsigned short* __restrict__ xg, const unsigned short* __restrict__ w13b,
    const int* __restrict__ offs, const int* __restrict__ work,
    unsigned short* __restrict__ hbuf)
{
    __shared__ __align__(16) unsigned short As[128 * 64];
    __shared__ __align__(16) unsigned short Bg[128 * 64];
    __shared__ __align__(16) unsigned short Bu[128 * 64];

    const int id = blockIdx.y * gridDim.x + blockIdx.x;   // 0..1151
    const int id2 = (id & 7) * 144 + (id >> 3);
    const int nt = id2 / 72;
    const int wki = id2 % 72;
    if (wki >= work[0]) return;
    const int wk = work[1 + wki];
    const int e = wk >> 8, mt = wk & 255;
    const int off_e = offs[e];
    const int cnt_e = offs[e + 1] - off_e;

    const int tid = threadIdx.x;
    const int w = tid >> 6, lane = tid & 63;
    const int ln15 = lane & 15, l16 = lane >> 4;
    const int wm = w >> 1, wn = w & 1;

    const unsigned short* aSrc[4]; const unsigned short* gSrc[4]; const unsigned short* uSrc[4];
    int ldsOff[4];
    #pragma unroll
    for (int i = 0; i < 4; ++i) {
        int S = (i * 4 + w) * 64 + lane;            // 16B chunk index, 0..1023
        int row = S >> 3;
        int ko = (S & 7) ^ (row & 7);               // inverse-swizzled slot
        ldsOff[i] = (i * 4 + w) * 512;              // wave-uniform base (ushorts)
        int tr = mt * 128 + row; if (tr >= cnt_e) tr = cnt_e - 1;
        aSrc[i] = xg + (size_t)(off_e + tr) * HDIM + ko * 8;
        gSrc[i] = w13b + (size_t)e * (2 * IDIM * HDIM) + (size_t)(nt * 128 + row) * HDIM + ko * 8;
        uSrc[i] = w13b + (size_t)e * (2 * IDIM * HDIM) + (size_t)(IDIM + nt * 128 + row) * HDIM + ko * 8;
    }

    const f32x4 z4 = {0.f, 0.f, 0.f, 0.f};
    f32x4 g[4][4], u[4][4];
    #pragma unroll
    for (int m = 0; m < 4; ++m)
        #pragma unroll
        for (int n = 0; n < 4; ++n) { g[m][n] = z4; u[m][n] = z4; }

    const int KT = HDIM / 64;   // 16
    for (int kt = 0; kt < KT; ++kt) {
        #pragma unroll
        for (int i = 0; i < 4; ++i) {
            gload_lds16(aSrc[i] + kt * 64, &As[ldsOff[i]]);
            gload_lds16(gSrc[i] + kt * 64, &Bg[ldsOff[i]]);
            gload_lds16(uSrc[i] + kt * 64, &Bu[ldsOff[i]]);
        }
        __syncthreads();
        #pragma unroll
        for (int kk = 0; kk < 2; ++kk) {
            short8 av[4], bgv[4], buv[4];
            int ko = kk * 4 + l16;
            #pragma unroll
            for (int m = 0; m < 4; ++m) {
                int row = wm * 64 + m * 16 + ln15;
                av[m] = *(const short8*)(As + row * 64 + ((ko ^ (row & 7)) * 8));
            }
            #pragma unroll
            for (int n = 0; n < 4; ++n) {
                int row = wn * 64 + n * 16 + ln15;
                int idx = row * 64 + ((ko ^ (row & 7)) * 8);
                bgv[n] = *(const short8*)(Bg + idx);
                buv[n] = *(const short8*)(Bu + idx);
            }
            __builtin_amdgcn_s_setprio(1);
            #pragma unroll
            for (int m = 0; m < 4; ++m)
                #pragma unroll
                for (int n = 0; n < 4; ++n) {
                    g[m][n] = MFMA16(av[m], bgv[n], g[m][n]);
                    u[m][n] = MFMA16(av[m], buv[n], u[m][n]);
                }
            __builtin_amdgcn_s_setprio(0);
        }
        __syncthreads();
    }

    // epilogue: h = silu(gate) * up -> bf16
    #pragma unroll
    for (int m = 0; m < 4; ++m) {
        #pragma unroll
        for (int i = 0; i < 4; ++i) {
            int r = mt * 128 + wm * 64 + m * 16 + l16 * 4 + i;
            if (r >= cnt_e) continue;
            size_t rb = (size_t)(off_e + r) * IDIM;
            #pragma unroll
            for (int n = 0; n < 4; ++n) {
                int col = nt * 128 + wn * 64 + n * 16 + ln15;
                float gv = g[m][n][i], uv = u[m][n][i];
                float hv = gv / (1.f + __expf(-gv)) * uv;
                hbuf[rb + col] = f2bf(hv);
            }
        }
    }
}

// ---------------- GEMM2: pb = bf16( tokw * (h @ W2^T) ) ----------------
// 128x128 tile, BK=64, 256 thr / 4 waves, single-buffer 32KB -> 4+ blocks/CU.
// grid (8, 72): work-list + XCD swizzle (nwg=576, q=72).

__global__ __launch_bounds__(256, 2) void gemm2_k(
    const unsigned short* __restrict__ hbuf, const unsigned short* __restrict__ w2b,
    const int* __restrict__ offs, const int* __restrict__ work,
    const float* __restrict__ tokw, unsigned short* __restrict__ pb)
{
    __shared__ __align__(16) unsigned short As[128 * 64];
    __shared__ __align__(16) unsigned short Bs[128 * 64];

    const int id = blockIdx.y * gridDim.x + blockIdx.x;   // 0..575
    const int id2 = (id & 7) * 72 + (id >> 3);
    const int nt = id2 / 72;
    const int wki = id2 % 72;
    if (wki >= work[0]) return;
    const int wk = work[1 + wki];
    const int e = wk >> 8, mt = wk & 255;
    const int off_e = offs[e];
    const int cnt_e = offs[e + 1] - off_e;

    const int tid = threadIdx.x;
    const int w = tid >> 6, lane = tid & 63;
    const int ln15 = lane & 15, l16 = lane >> 4;
    const int wm = w >> 1, wn = w & 1;

    const unsigned short* aSrc[4]; const unsigned short* bSrc[4];
    int ldsOff[4];
    #pragma unroll
    for (int i = 0; i < 4; ++i) {
        int S = (i * 4 + w) * 64 + lane;
        int row = S >> 3;
        int ko = (S & 7) ^ (row & 7);
        ldsOff[i] = (i * 4 + w) * 512;
        int tr = mt * 128 + row; if (tr >= cnt_e) tr = cnt_e - 1;
        aSrc[i] = hbuf + (size_t)(off_e + tr) * IDIM + ko * 8;
        bSrc[i] = w2b + (size_t)e * (HDIM * IDIM) + (size_t)(nt * 128 + row) * IDIM + ko * 8;
    }

    const f32x4 z4 = {0.f, 0.f, 0.f, 0.f};
    f32x4 acc[4][4];
    #pragma unroll
    for (int m = 0; m < 4; ++m)
        #pragma unroll
        for (int n = 0; n < 4; ++n) acc[m][n] = z4;

    const int KT = IDIM / 64;   // 32
    for (int kt = 0; kt < KT; ++kt) {
        #pragma unroll
        for (int i = 0; i < 4; ++i) {
            gload_lds16(aSrc[i] + kt * 64, &As[ldsOff[i]]);
            gload_lds16(bSrc[i] + kt * 64, &Bs[ldsOff[i]]);
        }
        __syncthreads();
        #pragma unroll
        for (int kk = 0; kk < 2; ++kk) {
            short8 av[4], bv[4];
            int ko = kk * 4 + l16;
            #pragma unroll
            for (int m = 0; m < 4; ++m) {
                int row = wm * 64 + m * 16 + ln15;
                av[m] = *(const short8*)(As + row * 64 + ((ko ^ (row & 7)) * 8));
            }
            #pragma unroll
            for (int n = 0; n < 4; ++n) {
                int row = wn * 64 + n * 16 + ln15;
                bv[n] = *(const short8*)(Bs + row * 64 + ((ko ^ (row & 7)) * 8));
            }
            __builtin_amdgcn_s_setprio(1);
            #pragma unroll
            for (int m = 0; m < 4; ++m)
                #pragma unroll
                for (int n = 0; n < 4; ++n)
                    acc[m][n] = MFMA16(av[m], bv[n], acc[m][n]);
            __builtin_amdgcn_s_setprio(0);
        }
        __syncthreads();
    }

    #pragma unroll
    for (int m = 0; m < 4; ++m) {
        #pragma unroll
        for (int i = 0; i < 4; ++i) {
            int r = mt * 128 + wm * 64 + m * 16 + l16 * 4 + i;
            if (r >= cnt_e) continue;
            float wgt = tokw[off_e + r];
            size_t rb = (size_t)(off_e + r) * HDIM;
            #pragma unroll
            for (int n = 0; n < 4; ++n) {
                int col = nt * 128 + wn * 64 + n * 16 + ln15;
                pb[rb + col] = f2bf(wgt * acc[m][n][i]);
            }
        }
    }
}

// ---------------- combine ----------------

__global__ void combine2_k(const unsigned short* __restrict__ pb, const int* __restrict__ pos,
                           float* __restrict__ out) {
    int idx = blockIdx.x * blockDim.x + threadIdx.x;   // T*H/8 threads
    int t = idx >> 7, c8 = idx & 127;
    int p0 = pos[2 * t], p1 = pos[2 * t + 1];
    short8 a = *(const short8*)(pb + (size_t)p0 * HDIM + c8 * 8);
    short8 b = *(const short8*)(pb + (size_t)p1 * HDIM + c8 * 8);
    float4 o0, o1;
    o0.x = bf2f((unsigned short)a[0]) + bf2f((unsigned short)b[0]);
    o0.y = bf2f((unsigned short)a[1]) + bf2f((unsigned short)b[1]);
    o0.z = bf2f((unsigned short)a[2]) + bf2f((unsigned short)b[2]);
    o0.w = bf2f((unsigned short)a[3]) + bf2f((unsigned short)b[3]);
    o1.x = bf2f((unsigned short)a[4]) + bf2f((unsigned short)b[4]);
    o1.y = bf2f((unsigned short)a[5]) + bf2f((unsigned short)b[5]);
    o1.z = bf2f((unsigned short)a[6]) + bf2f((unsigned short)b[6]);
    o1.w = bf2f((unsigned short)a[7]) + bf2f((unsigned short)b[7]);
    float* op = out + (size_t)t * HDIM + c8 * 8;
    ((float4*)op)[0] = o0;
    ((float4*)op)[1] = o1;
}

// ---------------- launch ----------------

extern "C" void kernel_launch(void* const* d_in, const int* in_sizes, int n_in,
                              void* d_out, int out_size, void* d_ws, size_t ws_size,
                              hipStream_t stream) {
    const float* x      = (const float*)d_in[0];
    const float* logits = (const float*)d_in[1];
    const float* w13    = (const float*)d_in[2];
    const float* w2     = (const float*)d_in[3];
    float* out = (float*)d_out;

    char* ws = (char*)d_ws;
    size_t off = 0;
    auto carve = [&](size_t bytes) -> void* {
        void* p = ws + off;
        off = (off + bytes + 255) & ~(size_t)255;
        return p;
    };
    int*   cnt    = (int*)carve(NEXP * 4);
    int*   offs   = (int*)carve((NEXP + 1) * 4);
    int*   cursor = (int*)carve(NEXP * 4);
    int*   work   = (int*)carve(128 * 4);
    int*   eids   = (int*)carve((size_t)T_TOK * 2 * 4);
    float* ews    = (float*)carve((size_t)T_TOK * 2 * 4);
    int*   tokid  = (int*)carve((size_t)(T_TOK * TOPK + 256) * 4);
    float* tokw   = (float*)carve((size_t)T_TOK * TOPK * 4);
    int*   pos    = (int*)carve((size_t)T_TOK * TOPK * 4);
    unsigned short* xg   = (unsigned short*)carve((size_t)T_TOK * TOPK * HDIM * 2);
    unsigned short* w13b = (unsigned short*)carve((size_t)NEXP * 2 * IDIM * HDIM * 2);
    unsigned short* w2b  = (unsigned short*)carve((size_t)NEXP * HDIM * IDIM * 2);
    unsigned short* hbuf = (unsigned short*)carve((size_t)T_TOK * TOPK * IDIM * 2);
    unsigned short* pb   = (unsigned short*)carve((size_t)T_TOK * TOPK * HDIM * 2);

    init_k<<<1, 64, 0, stream>>>(cnt);
    router_k<<<T_TOK / 256, 256, 0, stream>>>(logits, cnt, eids, ews);
    offs_k<<<1, 1, 0, stream>>>(cnt, offs, cursor, work);
    scatter_k<<<T_TOK / 256, 256, 0, stream>>>(eids, ews, cursor, tokid, tokw, pos);

    cvt_all_k<<<4096, 256, 0, stream>>>(x, w13, w2, tokid, xg, w13b, w2b);

    gemm1_k<<<dim3(16, 72, 1), 256, 0, stream>>>(xg, w13b, offs, work, hbuf);
    gemm2_k<<<dim3(8, 72, 1), 256, 0, stream>>>(hbuf, w2b, offs, work, tokw, pb);

    combine2_k<<<(T_TOK * HDIM / 8) / 256, 256, 0, stream>>>(pb, pos, out);
}

// Round 10
// 222.716 us; speedup vs baseline: 1.5288x; 1.2930x over previous
//
#include <hip/hip_runtime.h>
#include <hip/hip_bf16.h>
#include <stdint.h>

#define T_TOK 4096
#define NEXP  8
#define HDIM  1024
#define IDIM  2048
#define TOPK  2

typedef __attribute__((ext_vector_type(8))) short short8;
typedef __attribute__((ext_vector_type(4))) float f32x4;

__device__ __forceinline__ unsigned short f2bf(float f) {
    union { float f; unsigned int u; } v; v.f = f;
    unsigned int u = v.u;
    return (unsigned short)((u + 0x7fffu + ((u >> 16) & 1u)) >> 16);
}
__device__ __forceinline__ float bf2f(unsigned short s) {
    union { unsigned int u; float f; } v; v.u = ((unsigned int)s) << 16;
    return v.f;
}
__device__ __forceinline__ void gload_lds16(const void* g, void* l) {
    __builtin_amdgcn_global_load_lds(
        (const __attribute__((address_space(1))) unsigned int*)g,
        (__attribute__((address_space(3))) unsigned int*)l,
        16, 0, 0);
}
#define MFMA16(A, B, C) __builtin_amdgcn_mfma_f32_16x16x32_bf16(A, B, C, 0, 0, 0)

// ---------------- fused routing: softmax-top2 + counts + offsets + scatter ----------------
// single block, 1024 threads; LDS counters; builds (e,mt) work list for BM=128.

__global__ __launch_bounds__(1024) void route_k(
    const float* __restrict__ logits, int* __restrict__ offs, int* __restrict__ work,
    int* __restrict__ tokid, float* __restrict__ tokw, int* __restrict__ pos)
{
    __shared__ int cnt[NEXP];
    __shared__ int cur[NEXP];
    const int tid = threadIdx.x;
    if (tid < NEXP) cnt[tid] = 0;
    __syncthreads();

    int e0v[4], e1v[4];
    float w0v[4], w1v[4];
    #pragma unroll
    for (int it = 0; it < 4; ++it) {
        int t = tid + it * 1024;
        const float4* lp = (const float4*)(logits + (size_t)t * NEXP);
        float4 a = lp[0], b = lp[1];
        float l[NEXP] = {a.x, a.y, a.z, a.w, b.x, b.y, b.z, b.w};
        int e0 = 0; float b0 = l[0];
        #pragma unroll
        for (int e = 1; e < NEXP; ++e) if (l[e] > b0) { b0 = l[e]; e0 = e; }
        int e1 = -1; float b1 = -1e30f;
        #pragma unroll
        for (int e = 0; e < NEXP; ++e) { if (e == e0) continue; if (l[e] > b1) { b1 = l[e]; e1 = e; } }
        float tt = __expf(b1 - b0);
        float w0 = 1.0f / (1.0f + tt);
        e0v[it] = e0; e1v[it] = e1; w0v[it] = w0; w1v[it] = 1.0f - w0;
        atomicAdd(&cnt[e0], 1);
        atomicAdd(&cnt[e1], 1);
    }
    __syncthreads();
    if (tid == 0) {
        int s = 0, n = 0;
        for (int e = 0; e < NEXP; ++e) {
            offs[e] = s; cur[e] = s;
            int nm = (cnt[e] + 127) >> 7;
            for (int m = 0; m < nm; ++m) work[1 + n++] = (e << 8) | m;
            s += cnt[e];
        }
        offs[NEXP] = s;
        work[0] = n;
    }
    __syncthreads();
    #pragma unroll
    for (int it = 0; it < 4; ++it) {
        int t = tid + it * 1024;
        int p0 = atomicAdd(&cur[e0v[it]], 1);
        tokid[p0] = t; tokw[p0] = w0v[it]; pos[2 * t] = p0;
        int p1 = atomicAdd(&cur[e1v[it]], 1);
        tokid[p1] = t; tokw[p1] = w1v[it]; pos[2 * t + 1] = p1;
    }
}

// ---------------- cvt1: gather tokens (bf16, sorted) + convert w13 ----------------

__global__ void cvt1_k(const float* __restrict__ x, const float* __restrict__ w13,
                       const int* __restrict__ tokid, unsigned short* __restrict__ xg,
                       unsigned short* __restrict__ w13b) {
    const int n0 = T_TOK * TOPK * HDIM / 8;
    const int n1 = NEXP * 2 * IDIM * HDIM / 8;
    const int total = n0 + n1;
    for (int i = blockIdx.x * blockDim.x + threadIdx.x; i < total; i += gridDim.x * blockDim.x) {
        const float* s; unsigned short* d; size_t js, jd;
        if (i < n0) {
            int p = i >> 7, c8 = i & 127;
            s = x; d = xg;
            js = (size_t)tokid[p] * HDIM + (size_t)c8 * 8;
            jd = (size_t)i * 8;
        } else {
            int j = i - n0; s = w13; d = w13b; js = (size_t)j * 8; jd = js;
        }
        const float4* p4 = (const float4*)(s + js);
        float4 a = p4[0], b = p4[1];
        union { unsigned short us[8]; short8 v; } r;
        r.us[0] = f2bf(a.x); r.us[1] = f2bf(a.y); r.us[2] = f2bf(a.z); r.us[3] = f2bf(a.w);
        r.us[4] = f2bf(b.x); r.us[5] = f2bf(b.y); r.us[6] = f2bf(b.z); r.us[7] = f2bf(b.w);
        *(short8*)(d + jd) = r.v;
    }
}

// ---------------- g1c2: gemm1 (R9 structure, frozen) ∥ w2 conversion ----------------
// 1D grid: blocks [0,256) convert w2 fp32->bf16 (grid-stride); blocks [256,1408)
// run gemm1 128x128 tile, BK=64, 4 waves, single-buffer 48KB LDS, XCD swizzle.

#define CVTB 256
#define G1B  1152   // 16 nt x 72 work slots

__global__ __launch_bounds__(256, 2) void g1c2_k(
    const unsigned short* __restrict__ xg, const unsigned short* __restrict__ w13b,
    const float* __restrict__ w2, unsigned short* __restrict__ w2b,
    const int* __restrict__ offs, const int* __restrict__ work,
    unsigned short* __restrict__ hbuf)
{
    __shared__ __align__(16) unsigned short As[128 * 64];
    __shared__ __align__(16) unsigned short Bg[128 * 64];
    __shared__ __align__(16) unsigned short Bu[128 * 64];

    const int bid = blockIdx.x;
    if (bid < CVTB) {
        // ---- w2 conversion: 2,097,152 chunks over 65,536 threads = 32 iters
        const int n2 = NEXP * HDIM * IDIM / 8;
        for (int i = bid * 256 + threadIdx.x; i < n2; i += CVTB * 256) {
            const float4* p4 = (const float4*)(w2 + (size_t)i * 8);
            float4 a = p4[0], b = p4[1];
            union { unsigned short us[8]; short8 v; } r;
            r.us[0] = f2bf(a.x); r.us[1] = f2bf(a.y); r.us[2] = f2bf(a.z); r.us[3] = f2bf(a.w);
            r.us[4] = f2bf(b.x); r.us[5] = f2bf(b.y); r.us[6] = f2bf(b.z); r.us[7] = f2bf(b.w);
            *(short8*)(w2b + (size_t)i * 8) = r.v;
        }
        return;
    }

    // ---- gemm1
    const int id = bid - CVTB;                       // 0..1151
    const int id2 = (id & 7) * 144 + (id >> 3);      // XCD-chunked bijective swizzle
    const int nt = id2 / 72;
    const int wki = id2 % 72;
    if (wki >= work[0]) return;
    const int wk = work[1 + wki];
    const int e = wk >> 8, mt = wk & 255;
    const int off_e = offs[e];
    const int cnt_e = offs[e + 1] - off_e;

    const int tid = threadIdx.x;
    const int w = tid >> 6, lane = tid & 63;
    const int ln15 = lane & 15, l16 = lane >> 4;
    const int wm = w >> 1, wn = w & 1;

    const unsigned short* aSrc[4]; const unsigned short* gSrc[4]; const unsigned short* uSrc[4];
    int ldsOff[4];
    #pragma unroll
    for (int i = 0; i < 4; ++i) {
        int S = (i * 4 + w) * 64 + lane;
        int row = S >> 3;
        int ko = (S & 7) ^ (row & 7);
        ldsOff[i] = (i * 4 + w) * 512;
        int tr = mt * 128 + row; if (tr >= cnt_e) tr = cnt_e - 1;
        aSrc[i] = xg + (size_t)(off_e + tr) * HDIM + ko * 8;
        gSrc[i] = w13b + (size_t)e * (2 * IDIM * HDIM) + (size_t)(nt * 128 + row) * HDIM + ko * 8;
        uSrc[i] = w13b + (size_t)e * (2 * IDIM * HDIM) + (size_t)(IDIM + nt * 128 + row) * HDIM + ko * 8;
    }

    const f32x4 z4 = {0.f, 0.f, 0.f, 0.f};
    f32x4 g[4][4], u[4][4];
    #pragma unroll
    for (int m = 0; m < 4; ++m)
        #pragma unroll
        for (int n = 0; n < 4; ++n) { g[m][n] = z4; u[m][n] = z4; }

    const int KT = HDIM / 64;   // 16
    for (int kt = 0; kt < KT; ++kt) {
        #pragma unroll
        for (int i = 0; i < 4; ++i) {
            gload_lds16(aSrc[i] + kt * 64, &As[ldsOff[i]]);
            gload_lds16(gSrc[i] + kt * 64, &Bg[ldsOff[i]]);
            gload_lds16(uSrc[i] + kt * 64, &Bu[ldsOff[i]]);
        }
        __syncthreads();
        #pragma unroll
        for (int kk = 0; kk < 2; ++kk) {
            short8 av[4], bgv[4], buv[4];
            int ko = kk * 4 + l16;
            #pragma unroll
            for (int m = 0; m < 4; ++m) {
                int row = wm * 64 + m * 16 + ln15;
                av[m] = *(const short8*)(As + row * 64 + ((ko ^ (row & 7)) * 8));
            }
            #pragma unroll
            for (int n = 0; n < 4; ++n) {
                int row = wn * 64 + n * 16 + ln15;
                int idx = row * 64 + ((ko ^ (row & 7)) * 8);
                bgv[n] = *(const short8*)(Bg + idx);
                buv[n] = *(const short8*)(Bu + idx);
            }
            __builtin_amdgcn_s_setprio(1);
            #pragma unroll
            for (int m = 0; m < 4; ++m)
                #pragma unroll
                for (int n = 0; n < 4; ++n) {
                    g[m][n] = MFMA16(av[m], bgv[n], g[m][n]);
                    u[m][n] = MFMA16(av[m], buv[n], u[m][n]);
                }
            __builtin_amdgcn_s_setprio(0);
        }
        __syncthreads();
    }

    #pragma unroll
    for (int m = 0; m < 4; ++m) {
        #pragma unroll
        for (int i = 0; i < 4; ++i) {
            int r = mt * 128 + wm * 64 + m * 16 + l16 * 4 + i;
            if (r >= cnt_e) continue;
            size_t rb = (size_t)(off_e + r) * IDIM;
            #pragma unroll
            for (int n = 0; n < 4; ++n) {
                int col = nt * 128 + wn * 64 + n * 16 + ln15;
                float gv = g[m][n][i], uv = u[m][n][i];
                float hv = gv / (1.f + __expf(-gv)) * uv;
                hbuf[rb + col] = f2bf(hv);
            }
        }
    }
}

// ---------------- GEMM2: pb = bf16( tokw * (h @ W2^T) ) — R9 structure, frozen ----------------

__global__ __launch_bounds__(256, 2) void gemm2_k(
    const unsigned short* __restrict__ hbuf, const unsigned short* __restrict__ w2b,
    const int* __restrict__ offs, const int* __restrict__ work,
    const float* __restrict__ tokw, unsigned short* __restrict__ pb)
{
    __shared__ __align__(16) unsigned short As[128 * 64];
    __shared__ __align__(16) unsigned short Bs[128 * 64];

    const int id = blockIdx.y * gridDim.x + blockIdx.x;   // 0..575
    const int id2 = (id & 7) * 72 + (id >> 3);
    const int nt = id2 / 72;
    const int wki = id2 % 72;
    if (wki >= work[0]) return;
    const int wk = work[1 + wki];
    const int e = wk >> 8, mt = wk & 255;
    const int off_e = offs[e];
    const int cnt_e = offs[e + 1] - off_e;

    const int tid = threadIdx.x;
    const int w = tid >> 6, lane = tid & 63;
    const int ln15 = lane & 15, l16 = lane >> 4;
    const int wm = w >> 1, wn = w & 1;

    const unsigned short* aSrc[4]; const unsigned short* bSrc[4];
    int ldsOff[4];
    #pragma unroll
    for (int i = 0; i < 4; ++i) {
        int S = (i * 4 + w) * 64 + lane;
        int row = S >> 3;
        int ko = (S & 7) ^ (row & 7);
        ldsOff[i] = (i * 4 + w) * 512;
        int tr = mt * 128 + row; if (tr >= cnt_e) tr = cnt_e - 1;
        aSrc[i] = hbuf + (size_t)(off_e + tr) * IDIM + ko * 8;
        bSrc[i] = w2b + (size_t)e * (HDIM * IDIM) + (size_t)(nt * 128 + row) * IDIM + ko * 8;
    }

    const f32x4 z4 = {0.f, 0.f, 0.f, 0.f};
    f32x4 acc[4][4];
    #pragma unroll
    for (int m = 0; m < 4; ++m)
        #pragma unroll
        for (int n = 0; n < 4; ++n) acc[m][n] = z4;

    const int KT = IDIM / 64;   // 32
    for (int kt = 0; kt < KT; ++kt) {
        #pragma unroll
        for (int i = 0; i < 4; ++i) {
            gload_lds16(aSrc[i] + kt * 64, &As[ldsOff[i]]);
            gload_lds16(bSrc[i] + kt * 64, &Bs[ldsOff[i]]);
        }
        __syncthreads();
        #pragma unroll
        for (int kk = 0; kk < 2; ++kk) {
            short8 av[4], bv[4];
            int ko = kk * 4 + l16;
            #pragma unroll
            for (int m = 0; m < 4; ++m) {
                int row = wm * 64 + m * 16 + ln15;
                av[m] = *(const short8*)(As + row * 64 + ((ko ^ (row & 7)) * 8));
            }
            #pragma unroll
            for (int n = 0; n < 4; ++n) {
                int row = wn * 64 + n * 16 + ln15;
                bv[n] = *(const short8*)(Bs + row * 64 + ((ko ^ (row & 7)) * 8));
            }
            __builtin_amdgcn_s_setprio(1);
            #pragma unroll
            for (int m = 0; m < 4; ++m)
                #pragma unroll
                for (int n = 0; n < 4; ++n)
                    acc[m][n] = MFMA16(av[m], bv[n], acc[m][n]);
            __builtin_amdgcn_s_setprio(0);
        }
        __syncthreads();
    }

    #pragma unroll
    for (int m = 0; m < 4; ++m) {
        #pragma unroll
        for (int i = 0; i < 4; ++i) {
            int r = mt * 128 + wm * 64 + m * 16 + l16 * 4 + i;
            if (r >= cnt_e) continue;
            float wgt = tokw[off_e + r];
            size_t rb = (size_t)(off_e + r) * HDIM;
            #pragma unroll
            for (int n = 0; n < 4; ++n) {
                int col = nt * 128 + wn * 64 + n * 16 + ln15;
                pb[rb + col] = f2bf(wgt * acc[m][n][i]);
            }
        }
    }
}

// ---------------- combine ----------------

__global__ void combine2_k(const unsigned short* __restrict__ pb, const int* __restrict__ pos,
                           float* __restrict__ out) {
    int idx = blockIdx.x * blockDim.x + threadIdx.x;   // T*H/8 threads
    int t = idx >> 7, c8 = idx & 127;
    int p0 = pos[2 * t], p1 = pos[2 * t + 1];
    short8 a = *(const short8*)(pb + (size_t)p0 * HDIM + c8 * 8);
    short8 b = *(const short8*)(pb + (size_t)p1 * HDIM + c8 * 8);
    float4 o0, o1;
    o0.x = bf2f((unsigned short)a[0]) + bf2f((unsigned short)b[0]);
    o0.y = bf2f((unsigned short)a[1]) + bf2f((unsigned short)b[1]);
    o0.z = bf2f((unsigned short)a[2]) + bf2f((unsigned short)b[2]);
    o0.w = bf2f((unsigned short)a[3]) + bf2f((unsigned short)b[3]);
    o1.x = bf2f((unsigned short)a[4]) + bf2f((unsigned short)b[4]);
    o1.y = bf2f((unsigned short)a[5]) + bf2f((unsigned short)b[5]);
    o1.z = bf2f((unsigned short)a[6]) + bf2f((unsigned short)b[6]);
    o1.w = bf2f((unsigned short)a[7]) + bf2f((unsigned short)b[7]);
    float* op = out + (size_t)t * HDIM + c8 * 8;
    ((float4*)op)[0] = o0;
    ((float4*)op)[1] = o1;
}

// ---------------- launch ----------------

extern "C" void kernel_launch(void* const* d_in, const int* in_sizes, int n_in,
                              void* d_out, int out_size, void* d_ws, size_t ws_size,
                              hipStream_t stream) {
    const float* x      = (const float*)d_in[0];
    const float* logits = (const float*)d_in[1];
    const float* w13    = (const float*)d_in[2];
    const float* w2     = (const float*)d_in[3];
    float* out = (float*)d_out;

    char* ws = (char*)d_ws;
    size_t off = 0;
    auto carve = [&](size_t bytes) -> void* {
        void* p = ws + off;
        off = (off + bytes + 255) & ~(size_t)255;
        return p;
    };
    int*   offs   = (int*)carve((NEXP + 1) * 4);
    int*   work   = (int*)carve(128 * 4);
    int*   tokid  = (int*)carve((size_t)(T_TOK * TOPK + 256) * 4);
    float* tokw   = (float*)carve((size_t)T_TOK * TOPK * 4);
    int*   pos    = (int*)carve((size_t)T_TOK * TOPK * 4);
    unsigned short* xg   = (unsigned short*)carve((size_t)T_TOK * TOPK * HDIM * 2);
    unsigned short* w13b = (unsigned short*)carve((size_t)NEXP * 2 * IDIM * HDIM * 2);
    unsigned short* w2b  = (unsigned short*)carve((size_t)NEXP * HDIM * IDIM * 2);
    unsigned short* hbuf = (unsigned short*)carve((size_t)T_TOK * TOPK * IDIM * 2);
    unsigned short* pb   = (unsigned short*)carve((size_t)T_TOK * TOPK * HDIM * 2);

    route_k<<<1, 1024, 0, stream>>>(logits, offs, work, tokid, tokw, pos);
    cvt1_k<<<4096, 256, 0, stream>>>(x, w13, tokid, xg, w13b);
    g1c2_k<<<CVTB + G1B, 256, 0, stream>>>(xg, w13b, w2, w2b, offs, work, hbuf);
    gemm2_k<<<dim3(8, 72, 1), 256, 0, stream>>>(hbuf, w2b, offs, work, tokw, pb);
    combine2_k<<<(T_TOK * HDIM / 8) / 256, 256, 0, stream>>>(pb, pos, out);
}

// Round 11
// 217.598 us; speedup vs baseline: 1.5647x; 1.0235x over previous
//
#include <hip/hip_runtime.h>
#include <hip/hip_bf16.h>
#include <stdint.h>

#define T_TOK 4096
#define NEXP  8
#define HDIM  1024
#define IDIM  2048
#define TOPK  2

typedef __attribute__((ext_vector_type(8))) short short8;
typedef __attribute__((ext_vector_type(4))) float f32x4;

__device__ __forceinline__ unsigned short f2bf(float f) {
    union { float f; unsigned int u; } v; v.f = f;
    unsigned int u = v.u;
    return (unsigned short)((u + 0x7fffu + ((u >> 16) & 1u)) >> 16);
}
__device__ __forceinline__ void gload_lds16(const void* g, void* l) {
    __builtin_amdgcn_global_load_lds(
        (const __attribute__((address_space(1))) unsigned int*)g,
        (__attribute__((address_space(3))) unsigned int*)l,
        16, 0, 0);
}
#define MFMA16(A, B, C) __builtin_amdgcn_mfma_f32_16x16x32_bf16(A, B, C, 0, 0, 0)

// ---------------- prep: routing (block 0) ∥ x+w13 fp32->bf16 (blocks 1+) ----------------

__global__ __launch_bounds__(1024) void prep_k(
    const float* __restrict__ logits, const float* __restrict__ x,
    const float* __restrict__ w13, int* __restrict__ offs, int* __restrict__ work,
    int* __restrict__ tokid, float* __restrict__ tokw,
    unsigned short* __restrict__ xb, unsigned short* __restrict__ w13b)
{
    const int tid = threadIdx.x;
    if (blockIdx.x == 0) {
        // ---- fused routing: softmax-top2 + counts + offsets + work list + scatter
        __shared__ int cnt[NEXP];
        __shared__ int cur[NEXP];
        if (tid < NEXP) cnt[tid] = 0;
        __syncthreads();
        int e0v[4], e1v[4];
        float w0v[4], w1v[4];
        #pragma unroll
        for (int it = 0; it < 4; ++it) {
            int t = tid + it * 1024;
            const float4* lp = (const float4*)(logits + (size_t)t * NEXP);
            float4 a = lp[0], b = lp[1];
            float l[NEXP] = {a.x, a.y, a.z, a.w, b.x, b.y, b.z, b.w};
            int e0 = 0; float b0 = l[0];
            #pragma unroll
            for (int e = 1; e < NEXP; ++e) if (l[e] > b0) { b0 = l[e]; e0 = e; }
            int e1 = -1; float b1 = -1e30f;
            #pragma unroll
            for (int e = 0; e < NEXP; ++e) { if (e == e0) continue; if (l[e] > b1) { b1 = l[e]; e1 = e; } }
            float tt = __expf(b1 - b0);
            float w0 = 1.0f / (1.0f + tt);
            e0v[it] = e0; e1v[it] = e1; w0v[it] = w0; w1v[it] = 1.0f - w0;
            atomicAdd(&cnt[e0], 1);
            atomicAdd(&cnt[e1], 1);
        }
        __syncthreads();
        if (tid == 0) {
            int s = 0, n = 0;
            for (int e = 0; e < NEXP; ++e) {
                offs[e] = s; cur[e] = s;
                int nm = (cnt[e] + 127) >> 7;
                for (int m = 0; m < nm; ++m) work[1 + n++] = (e << 8) | m;
                s += cnt[e];
            }
            offs[NEXP] = s;
            work[0] = n;
        }
        __syncthreads();
        #pragma unroll
        for (int it = 0; it < 4; ++it) {
            int t = tid + it * 1024;
            int p0 = atomicAdd(&cur[e0v[it]], 1);
            tokid[p0] = t; tokw[p0] = w0v[it];
            int p1 = atomicAdd(&cur[e1v[it]], 1);
            tokid[p1] = t; tokw[p1] = w1v[it];
        }
        return;
    }
    // ---- conversions (no routing dependency): xb (dense) + w13b
    const int n0 = T_TOK * HDIM / 8;
    const int n1 = NEXP * 2 * IDIM * HDIM / 8;
    const int total = n0 + n1;
    for (int i = (blockIdx.x - 1) * 1024 + tid; i < total; i += (int)(gridDim.x - 1) * 1024) {
        const float* s; unsigned short* d; int j;
        if (i < n0) { s = x; d = xb; j = i; }
        else { s = w13; d = w13b; j = i - n0; }
        const float4* p4 = (const float4*)(s + (size_t)j * 8);
        float4 a = p4[0], b = p4[1];
        union { unsigned short us[8]; short8 v; } r;
        r.us[0] = f2bf(a.x); r.us[1] = f2bf(a.y); r.us[2] = f2bf(a.z); r.us[3] = f2bf(a.w);
        r.us[4] = f2bf(b.x); r.us[5] = f2bf(b.y); r.us[6] = f2bf(b.z); r.us[7] = f2bf(b.w);
        *(short8*)(d + (size_t)j * 8) = r.v;
    }
}

// ---------------- g1c2: gemm1 (frozen R9 structure) ∥ w2 conversion ----------------
// blocks [0,256): w2 fp32->bf16 grid-stride; blocks [256,1408): gemm1 128x128,
// BK=64, 4 waves, single-buffer 48KB LDS, XCD-chunked swizzle, tokid-indirect A.

#define CVTB 256
#define G1B  1152   // 16 nt x 72 work slots

__global__ __launch_bounds__(256, 2) void g1c2_k(
    const unsigned short* __restrict__ xb, const unsigned short* __restrict__ w13b,
    const float* __restrict__ w2, unsigned short* __restrict__ w2b,
    const int* __restrict__ tokid, const int* __restrict__ offs,
    const int* __restrict__ work, unsigned short* __restrict__ hbuf)
{
    __shared__ __align__(16) unsigned short As[128 * 64];
    __shared__ __align__(16) unsigned short Bg[128 * 64];
    __shared__ __align__(16) unsigned short Bu[128 * 64];

    const int bid = blockIdx.x;
    if (bid < CVTB) {
        const int n2 = NEXP * HDIM * IDIM / 8;
        for (int i = bid * 256 + threadIdx.x; i < n2; i += CVTB * 256) {
            const float4* p4 = (const float4*)(w2 + (size_t)i * 8);
            float4 a = p4[0], b = p4[1];
            union { unsigned short us[8]; short8 v; } r;
            r.us[0] = f2bf(a.x); r.us[1] = f2bf(a.y); r.us[2] = f2bf(a.z); r.us[3] = f2bf(a.w);
            r.us[4] = f2bf(b.x); r.us[5] = f2bf(b.y); r.us[6] = f2bf(b.z); r.us[7] = f2bf(b.w);
            *(short8*)(w2b + (size_t)i * 8) = r.v;
        }
        return;
    }

    const int id = bid - CVTB;                       // 0..1151
    const int id2 = (id & 7) * 144 + (id >> 3);      // XCD-chunked bijective swizzle
    const int nt = id2 / 72;
    const int wki = id2 % 72;
    if (wki >= work[0]) return;
    const int wk = work[1 + wki];
    const int e = wk >> 8, mt = wk & 255;
    const int off_e = offs[e];
    const int cnt_e = offs[e + 1] - off_e;

    const int tid = threadIdx.x;
    const int w = tid >> 6, lane = tid & 63;
    const int ln15 = lane & 15, l16 = lane >> 4;
    const int wm = w >> 1, wn = w & 1;

    const unsigned short* aSrc[4]; const unsigned short* gSrc[4]; const unsigned short* uSrc[4];
    int ldsOff[4];
    #pragma unroll
    for (int i = 0; i < 4; ++i) {
        int S = (i * 4 + w) * 64 + lane;
        int row = S >> 3;
        int ko = (S & 7) ^ (row & 7);
        ldsOff[i] = (i * 4 + w) * 512;
        int tr = mt * 128 + row; if (tr >= cnt_e) tr = cnt_e - 1;
        aSrc[i] = xb + (size_t)tokid[off_e + tr] * HDIM + ko * 8;
        gSrc[i] = w13b + (size_t)e * (2 * IDIM * HDIM) + (size_t)(nt * 128 + row) * HDIM + ko * 8;
        uSrc[i] = w13b + (size_t)e * (2 * IDIM * HDIM) + (size_t)(IDIM + nt * 128 + row) * HDIM + ko * 8;
    }

    const f32x4 z4 = {0.f, 0.f, 0.f, 0.f};
    f32x4 g[4][4], u[4][4];
    #pragma unroll
    for (int m = 0; m < 4; ++m)
        #pragma unroll
        for (int n = 0; n < 4; ++n) { g[m][n] = z4; u[m][n] = z4; }

    const int KT = HDIM / 64;   // 16
    for (int kt = 0; kt < KT; ++kt) {
        #pragma unroll
        for (int i = 0; i < 4; ++i) {
            gload_lds16(aSrc[i] + kt * 64, &As[ldsOff[i]]);
            gload_lds16(gSrc[i] + kt * 64, &Bg[ldsOff[i]]);
            gload_lds16(uSrc[i] + kt * 64, &Bu[ldsOff[i]]);
        }
        __syncthreads();
        #pragma unroll
        for (int kk = 0; kk < 2; ++kk) {
            short8 av[4], bgv[4], buv[4];
            int ko = kk * 4 + l16;
            #pragma unroll
            for (int m = 0; m < 4; ++m) {
                int row = wm * 64 + m * 16 + ln15;
                av[m] = *(const short8*)(As + row * 64 + ((ko ^ (row & 7)) * 8));
            }
            #pragma unroll
            for (int n = 0; n < 4; ++n) {
                int row = wn * 64 + n * 16 + ln15;
                int idx = row * 64 + ((ko ^ (row & 7)) * 8);
                bgv[n] = *(const short8*)(Bg + idx);
                buv[n] = *(const short8*)(Bu + idx);
            }
            __builtin_amdgcn_s_setprio(1);
            #pragma unroll
            for (int m = 0; m < 4; ++m)
                #pragma unroll
                for (int n = 0; n < 4; ++n) {
                    g[m][n] = MFMA16(av[m], bgv[n], g[m][n]);
                    u[m][n] = MFMA16(av[m], buv[n], u[m][n]);
                }
            __builtin_amdgcn_s_setprio(0);
        }
        __syncthreads();
    }

    #pragma unroll
    for (int m = 0; m < 4; ++m) {
        #pragma unroll
        for (int i = 0; i < 4; ++i) {
            int r = mt * 128 + wm * 64 + m * 16 + l16 * 4 + i;
            if (r >= cnt_e) continue;
            size_t rb = (size_t)(off_e + r) * IDIM;
            #pragma unroll
            for (int n = 0; n < 4; ++n) {
                int col = nt * 128 + wn * 64 + n * 16 + ln15;
                float gv = g[m][n][i], uv = u[m][n][i];
                float hv = gv / (1.f + __expf(-gv)) * uv;
                hbuf[rb + col] = f2bf(hv);
            }
        }
    }
}

// ---------------- gemm2c: (h @ W2^T) * tokw, fused combine via f32 atomicAdd ----------------
// 128x128 tile, BK=64, 4 waves, single-buffer 32KB. out must be pre-zeroed.
// Exactly 2 contributions per out element (commutative f32 add -> deterministic).

__global__ __launch_bounds__(256, 2) void gemm2c_k(
    const unsigned short* __restrict__ hbuf, const unsigned short* __restrict__ w2b,
    const int* __restrict__ tokid, const int* __restrict__ offs,
    const int* __restrict__ work, const float* __restrict__ tokw,
    float* __restrict__ out)
{
    __shared__ __align__(16) unsigned short As[128 * 64];
    __shared__ __align__(16) unsigned short Bs[128 * 64];

    const int id = blockIdx.y * gridDim.x + blockIdx.x;   // 0..575
    const int id2 = (id & 7) * 72 + (id >> 3);
    const int nt = id2 / 72;
    const int wki = id2 % 72;
    if (wki >= work[0]) return;
    const int wk = work[1 + wki];
    const int e = wk >> 8, mt = wk & 255;
    const int off_e = offs[e];
    const int cnt_e = offs[e + 1] - off_e;

    const int tid = threadIdx.x;
    const int w = tid >> 6, lane = tid & 63;
    const int ln15 = lane & 15, l16 = lane >> 4;
    const int wm = w >> 1, wn = w & 1;

    const unsigned short* aSrc[4]; const unsigned short* bSrc[4];
    int ldsOff[4];
    #pragma unroll
    for (int i = 0; i < 4; ++i) {
        int S = (i * 4 + w) * 64 + lane;
        int row = S >> 3;
        int ko = (S & 7) ^ (row & 7);
        ldsOff[i] = (i * 4 + w) * 512;
        int tr = mt * 128 + row; if (tr >= cnt_e) tr = cnt_e - 1;
        aSrc[i] = hbuf + (size_t)(off_e + tr) * IDIM + ko * 8;
        bSrc[i] = w2b + (size_t)e * (HDIM * IDIM) + (size_t)(nt * 128 + row) * IDIM + ko * 8;
    }

    const f32x4 z4 = {0.f, 0.f, 0.f, 0.f};
    f32x4 acc[4][4];
    #pragma unroll
    for (int m = 0; m < 4; ++m)
        #pragma unroll
        for (int n = 0; n < 4; ++n) acc[m][n] = z4;

    const int KT = IDIM / 64;   // 32
    for (int kt = 0; kt < KT; ++kt) {
        #pragma unroll
        for (int i = 0; i < 4; ++i) {
            gload_lds16(aSrc[i] + kt * 64, &As[ldsOff[i]]);
            gload_lds16(bSrc[i] + kt * 64, &Bs[ldsOff[i]]);
        }
        __syncthreads();
        #pragma unroll
        for (int kk = 0; kk < 2; ++kk) {
            short8 av[4], bv[4];
            int ko = kk * 4 + l16;
            #pragma unroll
            for (int m = 0; m < 4; ++m) {
                int row = wm * 64 + m * 16 + ln15;
                av[m] = *(const short8*)(As + row * 64 + ((ko ^ (row & 7)) * 8));
            }
            #pragma unroll
            for (int n = 0; n < 4; ++n) {
                int row = wn * 64 + n * 16 + ln15;
                bv[n] = *(const short8*)(Bs + row * 64 + ((ko ^ (row & 7)) * 8));
            }
            __builtin_amdgcn_s_setprio(1);
            #pragma unroll
            for (int m = 0; m < 4; ++m)
                #pragma unroll
                for (int n = 0; n < 4; ++n)
                    acc[m][n] = MFMA16(av[m], bv[n], acc[m][n]);
            __builtin_amdgcn_s_setprio(0);
        }
        __syncthreads();
    }

    // fused combine: out[tok] += tokw * acc  (2 contributions per element total)
    #pragma unroll
    for (int m = 0; m < 4; ++m) {
        #pragma unroll
        for (int i = 0; i < 4; ++i) {
            int r = mt * 128 + wm * 64 + m * 16 + l16 * 4 + i;
            if (r >= cnt_e) continue;
            int tok = tokid[off_e + r];
            float wgt = tokw[off_e + r];
            float* orow = out + (size_t)tok * HDIM;
            #pragma unroll
            for (int n = 0; n < 4; ++n) {
                int col = nt * 128 + wn * 64 + n * 16 + ln15;
                atomicAdd(&orow[col], wgt * acc[m][n][i]);
            }
        }
    }
}

// ---------------- launch ----------------

extern "C" void kernel_launch(void* const* d_in, const int* in_sizes, int n_in,
                              void* d_out, int out_size, void* d_ws, size_t ws_size,
                              hipStream_t stream) {
    const float* x      = (const float*)d_in[0];
    const float* logits = (const float*)d_in[1];
    const float* w13    = (const float*)d_in[2];
    const float* w2     = (const float*)d_in[3];
    float* out = (float*)d_out;

    char* ws = (char*)d_ws;
    size_t off = 0;
    auto carve = [&](size_t bytes) -> void* {
        void* p = ws + off;
        off = (off + bytes + 255) & ~(size_t)255;
        return p;
    };
    int*   offs   = (int*)carve((NEXP + 1) * 4);
    int*   work   = (int*)carve(128 * 4);
    int*   tokid  = (int*)carve((size_t)(T_TOK * TOPK + 256) * 4);
    float* tokw   = (float*)carve((size_t)T_TOK * TOPK * 4);
    unsigned short* xb   = (unsigned short*)carve((size_t)T_TOK * HDIM * 2);
    unsigned short* w13b = (unsigned short*)carve((size_t)NEXP * 2 * IDIM * HDIM * 2);
    unsigned short* w2b  = (unsigned short*)carve((size_t)NEXP * HDIM * IDIM * 2);
    unsigned short* hbuf = (unsigned short*)carve((size_t)T_TOK * TOPK * IDIM * 2);

    hipMemsetAsync(out, 0, (size_t)T_TOK * HDIM * sizeof(float), stream);
    prep_k<<<1024, 1024, 0, stream>>>(logits, x, w13, offs, work, tokid, tokw, xb, w13b);
    g1c2_k<<<CVTB + G1B, 256, 0, stream>>>(xb, w13b, w2, w2b, tokid, offs, work, hbuf);
    gemm2c_k<<<dim3(8, 72, 1), 256, 0, stream>>>(hbuf, w2b, tokid, offs, work, tokw, out);
}